// Round 1
// baseline (224.084 us; speedup 1.0000x reference)
//
#include <hip/hip_runtime.h>
#include <hip/hip_bf16.h>

// CBFHalfspace: h(x)=b-Ax with A[:,0:2]=[[-1,0],[1,0],[0,-1],[0,1]], b=[1,1,1,1].
// Since h is affine and A's column sums are zero, grad(sum h) == 0, so
// Lfh = Lf2h = LgLfh = 0 exactly. Per-row output (8 floats):
//   [1+x0, 1-x0, 1+x1, 1-x1, 0, 0, 0, 0]
// Pure memory-bound: read B*7 f32 (~117 MB), write B*8 f32 (~134 MB).

__global__ __launch_bounds__(256) void CBFHalfspace_68917045231689_kernel(
        const float* __restrict__ x, float* __restrict__ out, int B) {
    int i = blockIdx.x * blockDim.x + threadIdx.x;
    if (i >= B) return;

    // Row i of x is 7 floats; only x0, x1 are needed.
    // i*7 fits in int32: 4,194,304 * 7 = 29,360,128.
    const int xi = i * 7;
    const float x0 = x[xi + 0];
    const float x1 = x[xi + 1];

    float4 h = make_float4(1.0f + x0, 1.0f - x0, 1.0f + x1, 1.0f - x1);
    float4 z = make_float4(0.0f, 0.0f, 0.0f, 0.0f);

    // Output row i is 8 floats, 32-byte aligned -> two float4 stores.
    float4* o = reinterpret_cast<float4*>(out + (size_t)i * 8);
    o[0] = h;
    o[1] = z;
}

extern "C" void kernel_launch(void* const* d_in, const int* in_sizes, int n_in,
                              void* d_out, int out_size, void* d_ws, size_t ws_size,
                              hipStream_t stream) {
    const float* x = (const float*)d_in[0];
    // d_in[1] (f) and d_in[2] (g) are mathematically irrelevant: the gradient
    // of sum(h) is identically zero, so every term involving f/g is zero.
    float* out = (float*)d_out;

    const int B = in_sizes[0] / 7;
    const int block = 256;
    const int grid = (B + block - 1) / block;
    CBFHalfspace_68917045231689_kernel<<<grid, block, 0, stream>>>(x, out, B);
}